// Round 2
// baseline (142.551 us; speedup 1.0000x reference)
//
#include <hip/hip_runtime.h>

// Problem constants: B=16 batches, A=5 agents, C=512 channels, H=W=16.
#define NB 16
#define NA 5
#define NC 512
#define HW 256   // 16*16

typedef float f4 __attribute__((ext_vector_type(4)));
typedef _Float16 h8 __attribute__((ext_vector_type(8)));   // 8 fp16 = 16 B = one ds_read_b128

static __device__ __forceinline__ h8 splat8(_Float16 v) {
    h8 r = {v, v, v, v, v, v, v, v};
    return r;
}

// One rotation-grid bilinear sample of agent-j's staged slab at fractional
// coords (ixr, iyr), pre-scaled by the (per-thread-masked) stage-2 weight ws.
// Zero-padding semantics: out-of-range taps get weight 0, address clamped.
static __device__ __forceinline__ h8 rot_sample(const h8* __restrict__ src,
                                                float ixr, float iyr, float ws) {
    const float fx0 = floorf(ixr), fy0 = floorf(iyr);
    const float wx1 = ixr - fx0,   wy1 = iyr - fy0;
    const int ix0 = (int)fx0, iy0 = (int)fy0;
    const int ix1 = ix0 + 1,  iy1 = iy0 + 1;
    const float mx0 = (ix0 >= 0 && ix0 < 16) ? (1.0f - wx1) : 0.0f;
    const float mx1 = (ix1 >= 0 && ix1 < 16) ? wx1 : 0.0f;
    const float my0 = (iy0 >= 0 && iy0 < 16) ? (1.0f - wy1) * ws : 0.0f;  // fold ws
    const float my1 = (iy1 >= 0 && iy1 < 16) ? wy1 * ws : 0.0f;
    const int cx0 = min(max(ix0, 0), 15), cx1 = min(max(ix1, 0), 15);
    const int cy0 = min(max(iy0, 0), 15), cy1 = min(max(iy1, 0), 15);
    const h8 v00 = src[cy0 * 16 + cx0];
    const h8 v01 = src[cy0 * 16 + cx1];
    const h8 v10 = src[cy1 * 16 + cx0];
    const h8 v11 = src[cy1 * 16 + cx1];
    const h8 hx0 = splat8((_Float16)mx0), hx1 = splat8((_Float16)mx1);
    const h8 hy0 = splat8((_Float16)my0), hy1 = splat8((_Float16)my1);
    return (v00 * hx0 + v01 * hx1) * hy0 + (v10 * hx0 + v11 * hx1) * hy1;
}

// Block = (batch b, 8-channel group). 256 threads = one per pixel.
// Single barrier after staging; the two-stage warp is computed as
//   out(p) = sum_{s in 2x2} w_s * rotsample(p + delta_s)
// (exact algebraic collapse of grid_sample(grid_sample(.,rot),trans)),
// so the inner pair loop has NO barriers and deep load-level parallelism.
// LDS = 5 agents * 256 px * 8ch fp16 = 20480 B -> 8 blocks/CU capacity.
__global__ __launch_bounds__(256) void fafmimo_fuse_kernel(
    const float* __restrict__ feat,   // [A*B][C][256], feat[a*B+b] = local[b][a]
    const float* __restrict__ trans,  // [B][A][A][4][4]
    const int*   __restrict__ numa,   // [B][A], use [:,0]
    float*       __restrict__ out)    // [A*B][C][256]
{
    __shared__ h8 lds_src[NA][HW];    // 20 KiB, pixel-major, 8ch interleaved

    const int bx = blockIdx.x;
    const int b  = bx & (NB - 1);     // batch fastest: mixes imbalanced batches
    const int g  = bx >> 4;           // channel group 0..63
    const int c0 = g << 3;
    const int p  = threadIdx.x;       // pixel 0..255
    const int x  = p & 15, y = p >> 4;
    const int n  = numa[b * NA];      // num_agent_tensor[b, 0]

    // Stage all agents' 8-channel slab into LDS as fp16 (each HBM byte once).
#pragma unroll
    for (int a = 0; a < NA; ++a) {
        const float* src = feat + ((a * NB + b) * NC + c0) * HW + p;
        h8 v;
#pragma unroll
        for (int k = 0; k < 8; ++k) v[k] = (_Float16)src[k * HW];
        lds_src[a][p] = v;
    }
    __syncthreads();

    for (int i = 0; i < NA; ++i) {
        // residual: local feature (fp16 round-trip, ~2e-3 abs err, ok vs 0.1475)
        const h8 lv = lds_src[i][p];
        float acc[8];
#pragma unroll
        for (int k = 0; k < 8; ++k) acc[k] = (float)lv[k];

        if (i < n) {
            for (int j = 0; j < n; ++j) {
                if (j == i) continue;     // n, i, j are block-uniform: no divergence

                const f4* tw = (const f4*)(trans + (((b * NA) + i) * NA + j) * 16);
                const f4 row0 = tw[0];    // r00 r01 _ tx
                const f4 row1 = tw[1];    // r10 r11 _ ty
                const float r00 = row0.x, r01 = row0.y;
                const float r10 = row1.x, r11 = row1.y;

                // stage-2 (translation) constants
                const float dx = 0.25f * row0.w;
                const float dy = -0.25f * row1.w;
                const float fdx = floorf(dx), fdy = floorf(dy);
                const float tx1 = dx - fdx, tx0 = 1.0f - tx1;
                const float ty1 = dy - fdy, ty0 = 1.0f - ty1;
                const int ox = x + (int)fdx;
                const int oy = y + (int)fdy;
                const bool inx0 = (ox >= 0) && (ox < 16);
                const bool inx1 = (ox + 1 >= 0) && (ox + 1 < 16);
                const bool iny0 = (oy >= 0) && (oy < 16);
                const bool iny1 = (oy + 1 >= 0) && (oy + 1 < 16);
                const float ws00 = (inx0 && iny0) ? tx0 * ty0 : 0.0f;
                const float ws10 = (inx1 && iny0) ? tx1 * ty0 : 0.0f;
                const float ws01 = (inx0 && iny1) ? tx0 * ty1 : 0.0f;
                const float ws11 = (inx1 && iny1) ? tx1 * ty1 : 0.0f;

                // rotation coords at the 2x2 stage-2 tap positions (affine:
                // neighbors differ by rotation-matrix columns)
                const float fox = (float)ox - 7.5f;
                const float foy = (float)oy - 7.5f;
                const float bxr = r00 * fox + r01 * foy + 7.5f;
                const float byr = r10 * fox + r11 * foy + 7.5f;

                const h8* srcj = &lds_src[j][0];
                h8 pacc = rot_sample(srcj, bxr,             byr,             ws00);
                pacc   += rot_sample(srcj, bxr + r00,       byr + r10,       ws10);
                pacc   += rot_sample(srcj, bxr + r01,       byr + r11,       ws01);
                pacc   += rot_sample(srcj, bxr + r00 + r01, byr + r10 + r11, ws11);

#pragma unroll
                for (int k = 0; k < 8; ++k) acc[k] += (float)pacc[k];
            }
        }

        // store fused[b][i] -> out[i*B+b]
        float* dst = out + ((i * NB + b) * NC + c0) * HW + p;
#pragma unroll
        for (int k = 0; k < 8; ++k) dst[k * HW] = acc[k];
    }
}

extern "C" void kernel_launch(void* const* d_in, const int* in_sizes, int n_in,
                              void* d_out, int out_size, void* d_ws, size_t ws_size,
                              hipStream_t stream) {
    const float* feat  = (const float*)d_in[0];
    const float* trans = (const float*)d_in[1];
    const int*   numa  = (const int*)d_in[2];
    float* out = (float*)d_out;

    // grid: 16 batches x 64 channel-groups; batch varies fastest
    fafmimo_fuse_kernel<<<dim3(NB * (NC / 8)), dim3(256), 0, stream>>>(
        feat, trans, numa, out);
}

// Round 3
// 125.807 us; speedup vs baseline: 1.1331x; 1.1331x over previous
//
#include <hip/hip_runtime.h>

// Problem constants: B=16 batches, A=5 agents, C=512 channels, H=W=16.
#define NB 16
#define NA 5
#define NC 512
#define HW 256   // 16*16

typedef float f4 __attribute__((ext_vector_type(4)));
typedef _Float16 h8 __attribute__((ext_vector_type(8)));   // 8 fp16 = 16 B = ds_read_b128

static __device__ __forceinline__ h8 splat8(float v) {
    const _Float16 h = (_Float16)v;
    h8 r = {h, h, h, h, h, h, h, h};
    return r;
}

// One rotation-grid bilinear sample of a staged fp16 slab at fractional coords
// (ixr, iyr), pre-scaled by the stage-2 weight ws (already border-masked).
// Zero-padding: out-of-range taps get weight 0, addresses clamped (safe).
static __device__ __forceinline__ h8 rot_sample(const h8* __restrict__ src,
                                                float ixr, float iyr, float ws) {
    const float fx0 = floorf(ixr), fy0 = floorf(iyr);
    const float wx1 = ixr - fx0,   wy1 = iyr - fy0;
    const int ix0 = (int)fx0, iy0 = (int)fy0;
    const int ix1 = ix0 + 1,  iy1 = iy0 + 1;
    const float mx0 = (ix0 >= 0 && ix0 < 16) ? (1.0f - wx1) : 0.0f;
    const float mx1 = (ix1 >= 0 && ix1 < 16) ? wx1 : 0.0f;
    const float my0 = (iy0 >= 0 && iy0 < 16) ? (1.0f - wy1) * ws : 0.0f;  // fold ws
    const float my1 = (iy1 >= 0 && iy1 < 16) ? wy1 * ws : 0.0f;
    const int cx0 = min(max(ix0, 0), 15), cx1 = min(max(ix1, 0), 15);
    const int cy0 = min(max(iy0, 0), 15), cy1 = min(max(iy1, 0), 15);
    const h8 v00 = src[cy0 * 16 + cx0];
    const h8 v01 = src[cy0 * 16 + cx1];
    const h8 v10 = src[cy1 * 16 + cx0];
    const h8 v11 = src[cy1 * 16 + cx1];
    const h8 hx0 = splat8(mx0), hx1 = splat8(mx1);
    const h8 hy0 = splat8(my0), hy1 = splat8(my1);
    return (v00 * hx0 + v01 * hx1) * hy0 + (v10 * hx0 + v11 * hx1) * hy1;
}

// Block = (output agent i, batch b, 8-channel group g). 256 threads = 1/pixel.
// Each block: exact-f32 residual + up to 4 collapsed warp-pairs (barrier-free
// after a single staging barrier). Work per block is 0..4 pairs (vs 0..20 for
// a per-batch block) -> much smoother load balance; grid 5120 = 20 slots/CU.
// LDS: up to 4 neighbor slabs, fp16 pixel-major 8ch-interleaved = 16 KiB.
__global__ __launch_bounds__(256) void fafmimo_pair_kernel(
    const float* __restrict__ feat,   // [A*B][C][256], feat[a*B+b] = local[b][a]
    const float* __restrict__ trans,  // [B][A][A][4][4]
    const int*   __restrict__ numa,   // [B][A], use [:,0]
    float*       __restrict__ out)    // [A*B][C][256]
{
    __shared__ h8 lds_nb[4][HW];      // 16 KiB

    const int bx = blockIdx.x;
    const int i  = bx % NA;           // output agent fastest: same-(b,g) blocks
    const int b  = (bx / NA) & (NB - 1);  //   adjacent -> L2/L3 reuse of slabs
    const int g  = bx / (NA * NB);    // channel group 0..63
    const int c0 = g << 3;
    const int p  = threadIdx.x;       // pixel 0..255
    const int x  = p & 15, y = p >> 4;
    const int n  = numa[b * NA];      // block-uniform

    // Residual: own slab in exact f32 (i>=n outputs are bit-exact copies).
    const float* own = feat + ((i * NB + b) * NC + c0) * HW + p;
    float acc[8];
#pragma unroll
    for (int k = 0; k < 8; ++k) acc[k] = own[k * HW];

    if (i < n && n > 1) {
        // Stage neighbor slabs (j < n, j != i) as fp16, slot s = j - (j>i).
        for (int j = 0; j < n; ++j) {     // n, i block-uniform: no divergence
            if (j == i) continue;
            const int s = j - (j > i);
            const float* src = feat + ((j * NB + b) * NC + c0) * HW + p;
            h8 v;
#pragma unroll
            for (int k = 0; k < 8; ++k) v[k] = (_Float16)src[k * HW];
            lds_nb[s][p] = v;
        }
        __syncthreads();

        for (int j = 0; j < n; ++j) {
            if (j == i) continue;
            const int s = j - (j > i);

            const f4* tw = (const f4*)(trans + (((b * NA) + i) * NA + j) * 16);
            const f4 row0 = tw[0];    // r00 r01 _ tx
            const f4 row1 = tw[1];    // r10 r11 _ ty
            const float r00 = row0.x, r01 = row0.y;
            const float r10 = row1.x, r11 = row1.y;

            // stage-2 (translation) constants
            const float dx = 0.25f * row0.w;
            const float dy = -0.25f * row1.w;
            const float fdx = floorf(dx), fdy = floorf(dy);
            const float tx1 = dx - fdx, tx0 = 1.0f - tx1;
            const float ty1 = dy - fdy, ty0 = 1.0f - ty1;
            const int ox = x + (int)fdx;
            const int oy = y + (int)fdy;
            const bool inx0 = (ox >= 0) && (ox < 16);
            const bool inx1 = (ox + 1 >= 0) && (ox + 1 < 16);
            const bool iny0 = (oy >= 0) && (oy < 16);
            const bool iny1 = (oy + 1 >= 0) && (oy + 1 < 16);
            const float ws00 = (inx0 && iny0) ? tx0 * ty0 : 0.0f;
            const float ws10 = (inx1 && iny0) ? tx1 * ty0 : 0.0f;
            const float ws01 = (inx0 && iny1) ? tx0 * ty1 : 0.0f;
            const float ws11 = (inx1 && iny1) ? tx1 * ty1 : 0.0f;

            // rotation coords at the 2x2 stage-2 tap positions
            const float fox = (float)ox - 7.5f;
            const float foy = (float)oy - 7.5f;
            const float bxr = r00 * fox + r01 * foy + 7.5f;
            const float byr = r10 * fox + r11 * foy + 7.5f;

            const h8* srcj = &lds_nb[s][0];
            h8 pacc = rot_sample(srcj, bxr,             byr,             ws00);
            pacc   += rot_sample(srcj, bxr + r00,       byr + r10,       ws10);
            pacc   += rot_sample(srcj, bxr + r01,       byr + r11,       ws01);
            pacc   += rot_sample(srcj, bxr + r00 + r01, byr + r10 + r11, ws11);

#pragma unroll
            for (int k = 0; k < 8; ++k) acc[k] += (float)pacc[k];
        }
    }

    // store fused[b][i] -> out[i*B+b]
    float* dst = out + ((i * NB + b) * NC + c0) * HW + p;
#pragma unroll
    for (int k = 0; k < 8; ++k) dst[k * HW] = acc[k];
}

extern "C" void kernel_launch(void* const* d_in, const int* in_sizes, int n_in,
                              void* d_out, int out_size, void* d_ws, size_t ws_size,
                              hipStream_t stream) {
    const float* feat  = (const float*)d_in[0];
    const float* trans = (const float*)d_in[1];
    const int*   numa  = (const int*)d_in[2];
    float* out = (float*)d_out;

    // grid: 5 agents x 16 batches x 64 channel-groups = 5120 blocks
    fafmimo_pair_kernel<<<dim3(NA * NB * (NC / 8)), dim3(256), 0, stream>>>(
        feat, trans, numa, out);
}

// Round 4
// 102.777 us; speedup vs baseline: 1.3870x; 1.2241x over previous
//
#include <hip/hip_runtime.h>

// Problem constants: B=16 batches, A=5 agents, C=512 channels, H=W=16.
#define NB 16
#define NA 5
#define NC 512
#define HW 256        // 16*16
#define NBLK 2560     // persistent-ish grid: 10 blocks/CU demanded, 8 resident
#define NITEM 2       // items per block; NBLK*NITEM = 5*16*64 = 5120 items

typedef float f4 __attribute__((ext_vector_type(4)));
typedef _Float16 h8 __attribute__((ext_vector_type(8)));   // 16 B = one ds_read_b128

static __device__ __forceinline__ h8 splat8(float v) {
    const _Float16 h = (_Float16)v;
    h8 r = {h, h, h, h, h, h, h, h};
    return r;
}

// One rotation-grid bilinear sample of a staged fp16 slab at fractional coords
// (ixr, iyr), pre-scaled by the stage-2 weight ws (already border-masked).
// Zero-padding: out-of-range taps get weight 0, addresses clamped (safe).
static __device__ __forceinline__ h8 rot_sample(const h8* __restrict__ src,
                                                float ixr, float iyr, float ws) {
    const float fx0 = floorf(ixr), fy0 = floorf(iyr);
    const float wx1 = ixr - fx0,   wy1 = iyr - fy0;
    const int ix0 = (int)fx0, iy0 = (int)fy0;
    const int ix1 = ix0 + 1,  iy1 = iy0 + 1;
    const float mx0 = (ix0 >= 0 && ix0 < 16) ? (1.0f - wx1) : 0.0f;
    const float mx1 = (ix1 >= 0 && ix1 < 16) ? wx1 : 0.0f;
    const float my0 = (iy0 >= 0 && iy0 < 16) ? (1.0f - wy1) * ws : 0.0f;  // fold ws
    const float my1 = (iy1 >= 0 && iy1 < 16) ? wy1 * ws : 0.0f;
    const int cx0 = min(max(ix0, 0), 15), cx1 = min(max(ix1, 0), 15);
    const int cy0 = min(max(iy0, 0), 15), cy1 = min(max(iy1, 0), 15);
    const h8 v00 = src[cy0 * 16 + cx0];
    const h8 v01 = src[cy0 * 16 + cx1];
    const h8 v10 = src[cy1 * 16 + cx0];
    const h8 v11 = src[cy1 * 16 + cx1];
    const h8 hx0 = splat8(mx0), hx1 = splat8(mx1);
    const h8 hy0 = splat8(my0), hy1 = splat8(my1);
    return (v00 * hx0 + v01 * hx1) * hy0 + (v10 * hx0 + v11 * hx1) * hy1;
}

// Persistent-style: each block handles NITEM items (i,b,g) via grid stride.
// item = g + 64*(i + 5*b): consecutive blocks share (i,b) (heavy pairs spread
// round-robin over CUs); the stride partner differs by b+8 (decorrelated n ->
// heavy+light mixing inside each block). Barrier-free pair math (collapsed
// two-stage warp); single staging barrier per worked item.
__global__ __launch_bounds__(256) void fafmimo_persist_kernel(
    const float* __restrict__ feat,   // [A*B][C][256], feat[a*B+b] = local[b][a]
    const float* __restrict__ trans,  // [B][A][A][4][4]
    const int*   __restrict__ numa,   // [B][A], use [:,0]
    float*       __restrict__ out)    // [A*B][C][256]
{
    __shared__ h8 lds_nb[4][HW];      // 16 KiB: up to 4 neighbor slabs

    const int p = threadIdx.x;        // pixel 0..255
    const int x = p & 15, y = p >> 4;
    bool lds_dirty = false;           // block-uniform

#pragma unroll
    for (int it = 0; it < NITEM; ++it) {
        const int item = blockIdx.x + it * NBLK;
        const int g  = item & 63;     // channel group
        const int r  = item >> 6;     // 0..79
        const int i  = r % NA;        // output agent
        const int b  = r / NA;        // batch
        const int c0 = g << 3;
        const int n  = numa[b * NA];  // block-uniform
        const bool work = (i < n) && (n > 1);

        // Residual: own slab, exact f32 (issued early, independent of LDS).
        const float* own = feat + ((i * NB + b) * NC + c0) * HW + p;
        float acc[8];
#pragma unroll
        for (int k = 0; k < 8; ++k) acc[k] = own[k * HW];

        if (work) {
            if (lds_dirty) __syncthreads();   // prev item's readers done
            // Stage neighbor slabs + hoist trans rows (latency overlapped).
            f4 r0v[4], r1v[4];
#pragma unroll
            for (int jj = 0; jj < 4; ++jj) {
                const int j = jj + (jj >= i);
                if (j < n) {                  // uniform: scalar-branch skip
                    const f4* tw = (const f4*)(trans + (((b * NA) + i) * NA + j) * 16);
                    r0v[jj] = tw[0];          // r00 r01 _ tx
                    r1v[jj] = tw[1];          // r10 r11 _ ty
                    const float* src = feat + ((j * NB + b) * NC + c0) * HW + p;
                    h8 v;
#pragma unroll
                    for (int k = 0; k < 8; ++k) v[k] = (_Float16)src[k * HW];
                    lds_nb[jj][p] = v;
                }
            }
            __syncthreads();
            lds_dirty = true;

            h8 pair_acc = splat8(0.0f);       // fp16 pair accumulation
#pragma unroll
            for (int jj = 0; jj < 4; ++jj) {
                const int j = jj + (jj >= i);
                if (j < n) {
                    const float r00 = r0v[jj].x, r01 = r0v[jj].y;
                    const float r10 = r1v[jj].x, r11 = r1v[jj].y;

                    // stage-2 (translation) constants
                    const float dx = 0.25f * r0v[jj].w;
                    const float dy = -0.25f * r1v[jj].w;
                    const float fdx = floorf(dx), fdy = floorf(dy);
                    const float tx1 = dx - fdx, tx0 = 1.0f - tx1;
                    const float ty1 = dy - fdy, ty0 = 1.0f - ty1;
                    const int ox = x + (int)fdx;
                    const int oy = y + (int)fdy;
                    const bool inx0 = (ox >= 0) && (ox < 16);
                    const bool inx1 = (ox + 1 >= 0) && (ox + 1 < 16);
                    const bool iny0 = (oy >= 0) && (oy < 16);
                    const bool iny1 = (oy + 1 >= 0) && (oy + 1 < 16);
                    const float ws00 = (inx0 && iny0) ? tx0 * ty0 : 0.0f;
                    const float ws10 = (inx1 && iny0) ? tx1 * ty0 : 0.0f;
                    const float ws01 = (inx0 && iny1) ? tx0 * ty1 : 0.0f;
                    const float ws11 = (inx1 && iny1) ? tx1 * ty1 : 0.0f;

                    // rotation coords at the 2x2 stage-2 tap positions
                    const float fox = (float)ox - 7.5f;
                    const float foy = (float)oy - 7.5f;
                    const float bxr = r00 * fox + r01 * foy + 7.5f;
                    const float byr = r10 * fox + r11 * foy + 7.5f;

                    const h8* srcj = &lds_nb[jj][0];
                    pair_acc += rot_sample(srcj, bxr,             byr,             ws00);
                    pair_acc += rot_sample(srcj, bxr + r00,       byr + r10,       ws10);
                    pair_acc += rot_sample(srcj, bxr + r01,       byr + r11,       ws01);
                    pair_acc += rot_sample(srcj, bxr + r00 + r01, byr + r10 + r11, ws11);
                }
            }
#pragma unroll
            for (int k = 0; k < 8; ++k) acc[k] += (float)pair_acc[k];
        }

        // store fused[b][i] -> out[i*B+b]
        float* dst = out + ((i * NB + b) * NC + c0) * HW + p;
#pragma unroll
        for (int k = 0; k < 8; ++k) dst[k * HW] = acc[k];
    }
}

extern "C" void kernel_launch(void* const* d_in, const int* in_sizes, int n_in,
                              void* d_out, int out_size, void* d_ws, size_t ws_size,
                              hipStream_t stream) {
    const float* feat  = (const float*)d_in[0];
    const float* trans = (const float*)d_in[1];
    const int*   numa  = (const int*)d_in[2];
    float* out = (float*)d_out;

    fafmimo_persist_kernel<<<dim3(NBLK), dim3(256), 0, stream>>>(
        feat, trans, numa, out);
}

// Round 5
// 99.926 us; speedup vs baseline: 1.4266x; 1.0285x over previous
//
#include <hip/hip_runtime.h>

// Problem constants: B=16 batches, A=5 agents, C=512 channels, H=W=16.
#define NB 16
#define NA 5
#define NC 512
#define HW 256        // 16*16
#define NBLK 2048     // exactly 8 blocks/CU worth of grid; items via stride
#define NTOT 5120     // 5*16*64 8-channel items

typedef float f4 __attribute__((ext_vector_type(4)));
typedef _Float16 h8 __attribute__((ext_vector_type(8)));   // 16 B = one ds_read_b128

static __device__ __forceinline__ h8 splat8(float v) {
    const _Float16 h = (_Float16)v;
    h8 r = {h, h, h, h, h, h, h, h};
    return r;
}

// Two bilinear samples of a staged fp16 slab, batched: all 8 addresses and all
// 8 masked weights are computed BEFORE the 8 ds_read_b128 are issued, so the
// loads go out back-to-back (ILP) instead of load-use chains.
// ws* are the stage-2 weights (already border-masked); zero-padding via
// weight=0 + clamped address.
static __device__ __forceinline__ h8 rot_sample2(const h8* __restrict__ src,
        float xA, float yA, float wA,
        float xB, float yB, float wB) {
    const float fxA = floorf(xA), fyA = floorf(yA);
    const float fxB = floorf(xB), fyB = floorf(yB);
    const int ixA = (int)fxA, iyA = (int)fyA;
    const int ixB = (int)fxB, iyB = (int)fyB;
    const float wxA1 = xA - fxA, wyA1 = yA - fyA;
    const float wxB1 = xB - fxB, wyB1 = yB - fyB;
    const float mxA0 = (ixA     >= 0 && ixA     < 16) ? 1.0f - wxA1 : 0.0f;
    const float mxA1 = (ixA + 1 >= 0 && ixA + 1 < 16) ? wxA1 : 0.0f;
    const float myA0 = (iyA     >= 0 && iyA     < 16) ? (1.0f - wyA1) * wA : 0.0f;
    const float myA1 = (iyA + 1 >= 0 && iyA + 1 < 16) ? wyA1 * wA : 0.0f;
    const float mxB0 = (ixB     >= 0 && ixB     < 16) ? 1.0f - wxB1 : 0.0f;
    const float mxB1 = (ixB + 1 >= 0 && ixB + 1 < 16) ? wxB1 : 0.0f;
    const float myB0 = (iyB     >= 0 && iyB     < 16) ? (1.0f - wyB1) * wB : 0.0f;
    const float myB1 = (iyB + 1 >= 0 && iyB + 1 < 16) ? wyB1 * wB : 0.0f;
    const int cxA0 = min(max(ixA, 0), 15), cxA1 = min(max(ixA + 1, 0), 15);
    const int cyA0 = min(max(iyA, 0), 15), cyA1 = min(max(iyA + 1, 0), 15);
    const int cxB0 = min(max(ixB, 0), 15), cxB1 = min(max(ixB + 1, 0), 15);
    const int cyB0 = min(max(iyB, 0), 15), cyB1 = min(max(iyB + 1, 0), 15);
    // 8 independent LDS loads
    const h8 vA00 = src[cyA0 * 16 + cxA0];
    const h8 vA01 = src[cyA0 * 16 + cxA1];
    const h8 vA10 = src[cyA1 * 16 + cxA0];
    const h8 vA11 = src[cyA1 * 16 + cxA1];
    const h8 vB00 = src[cyB0 * 16 + cxB0];
    const h8 vB01 = src[cyB0 * 16 + cxB1];
    const h8 vB10 = src[cyB1 * 16 + cxB0];
    const h8 vB11 = src[cyB1 * 16 + cxB1];
    return (vA00 * splat8(mxA0) + vA01 * splat8(mxA1)) * splat8(myA0)
         + (vA10 * splat8(mxA0) + vA11 * splat8(mxA1)) * splat8(myA1)
         + (vB00 * splat8(mxB0) + vB01 * splat8(mxB1)) * splat8(myB0)
         + (vB10 * splat8(mxB0) + vB11 * splat8(mxB1)) * splat8(myB1);
}

struct Item {
    int i, b, c0, n;
    bool work;
    float own[8];      // residual slab (exact f32)
    float nb[4][8];    // neighbor slabs (this thread's pixel), f32 until LDS write
    f4 r0[4], r1[4];   // trans rows per pair slot
};

// Issue all global loads for item `idx`; values land later (regs), hidden by
// the previous item's gather phase.
static __device__ __forceinline__ Item prefetch_item(
        const float* __restrict__ feat, const float* __restrict__ trans,
        const int* __restrict__ numa, int idx, int p) {
    Item it;
    const int g = idx & 63;
    const int r = idx >> 6;
    it.i = r % NA;
    it.b = r / NA;
    it.c0 = g << 3;
    it.n = numa[it.b * NA];
    it.work = (it.i < it.n) && (it.n > 1);
    const float* own = feat + ((it.i * NB + it.b) * NC + it.c0) * HW + p;
#pragma unroll
    for (int k = 0; k < 8; ++k) it.own[k] = own[k * HW];
    if (it.work) {
#pragma unroll
        for (int jj = 0; jj < 4; ++jj) {
            const int j = jj + (jj >= it.i);
            if (j < it.n) {                    // block-uniform
                const f4* tw = (const f4*)(trans + (((it.b * NA) + it.i) * NA + j) * 16);
                it.r0[jj] = tw[0];             // r00 r01 _ tx
                it.r1[jj] = tw[1];             // r10 r11 _ ty
                const float* src = feat + ((j * NB + it.b) * NC + it.c0) * HW + p;
#pragma unroll
                for (int k = 0; k < 8; ++k) it.nb[jj][k] = src[k * HW];
            }
        }
    }
    return it;
}

// Block = 256 threads (one/pixel). Grid 2048 = 8 blocks/CU; each block
// processes items idx, idx+2048, idx+4096 with register prefetch pipelining:
// item k+1's global loads are in flight while item k's LDS gathers execute.
__global__ __launch_bounds__(256) void fafmimo_pipe_kernel(
    const float* __restrict__ feat,   // [A*B][C][256], feat[a*B+b] = local[b][a]
    const float* __restrict__ trans,  // [B][A][A][4][4]
    const int*   __restrict__ numa,   // [B][A], use [:,0]
    float*       __restrict__ out)    // [A*B][C][256]
{
    __shared__ h8 lds_nb[4][HW];      // 16 KiB

    const int p = threadIdx.x;
    const int x = p & 15, y = p >> 4;
    bool dirty = false;               // block-uniform

    int idx = blockIdx.x;
    Item cur = prefetch_item(feat, trans, numa, idx, p);

    while (true) {
        // ---- LDS write phase for cur ----
        if (cur.work) {
            if (dirty) __syncthreads();       // previous item's readers done
#pragma unroll
            for (int jj = 0; jj < 4; ++jj) {
                const int j = jj + (jj >= cur.i);
                if (j < cur.n) {
                    h8 v;
#pragma unroll
                    for (int k = 0; k < 8; ++k) v[k] = (_Float16)cur.nb[jj][k];
                    lds_nb[jj][p] = v;
                }
            }
            __syncthreads();
            dirty = true;
        }

        // ---- prefetch next item (loads overlap the gather phase below) ----
        const int nidx = idx + NBLK;
        const bool more = nidx < NTOT;        // block-uniform
        Item nxt;
        if (more) nxt = prefetch_item(feat, trans, numa, nidx, p);

        // ---- gather + store for cur ----
        float acc[8];
#pragma unroll
        for (int k = 0; k < 8; ++k) acc[k] = cur.own[k];

        if (cur.work) {
            h8 pair_acc = splat8(0.0f);
#pragma unroll
            for (int jj = 0; jj < 4; ++jj) {
                const int j = jj + (jj >= cur.i);
                if (j < cur.n) {
                    const float r00 = cur.r0[jj].x, r01 = cur.r0[jj].y;
                    const float r10 = cur.r1[jj].x, r11 = cur.r1[jj].y;

                    // stage-2 (translation) constants
                    const float dx = 0.25f * cur.r0[jj].w;
                    const float dy = -0.25f * cur.r1[jj].w;
                    const float fdx = floorf(dx), fdy = floorf(dy);
                    const float tx1 = dx - fdx, tx0 = 1.0f - tx1;
                    const float ty1 = dy - fdy, ty0 = 1.0f - ty1;
                    const int ox = x + (int)fdx;
                    const int oy = y + (int)fdy;
                    const bool inx0 = (ox >= 0) && (ox < 16);
                    const bool inx1 = (ox + 1 >= 0) && (ox + 1 < 16);
                    const bool iny0 = (oy >= 0) && (oy < 16);
                    const bool iny1 = (oy + 1 >= 0) && (oy + 1 < 16);
                    const float ws00 = (inx0 && iny0) ? tx0 * ty0 : 0.0f;
                    const float ws10 = (inx1 && iny0) ? tx1 * ty0 : 0.0f;
                    const float ws01 = (inx0 && iny1) ? tx0 * ty1 : 0.0f;
                    const float ws11 = (inx1 && iny1) ? tx1 * ty1 : 0.0f;

                    // rotation coords at the 2x2 stage-2 tap positions
                    const float fox = (float)ox - 7.5f;
                    const float foy = (float)oy - 7.5f;
                    const float bxr = r00 * fox + r01 * foy + 7.5f;
                    const float byr = r10 * fox + r11 * foy + 7.5f;

                    const h8* srcj = &lds_nb[jj][0];
                    pair_acc += rot_sample2(srcj,
                        bxr,       byr,       ws00,
                        bxr + r00, byr + r10, ws10);
                    pair_acc += rot_sample2(srcj,
                        bxr + r01,       byr + r11,       ws01,
                        bxr + r00 + r01, byr + r10 + r11, ws11);
                }
            }
#pragma unroll
            for (int k = 0; k < 8; ++k) acc[k] += (float)pair_acc[k];
        }

        float* dst = out + ((cur.i * NB + cur.b) * NC + cur.c0) * HW + p;
#pragma unroll
        for (int k = 0; k < 8; ++k) dst[k * HW] = acc[k];

        if (!more) break;
        cur = nxt;
        idx = nidx;
    }
}

extern "C" void kernel_launch(void* const* d_in, const int* in_sizes, int n_in,
                              void* d_out, int out_size, void* d_ws, size_t ws_size,
                              hipStream_t stream) {
    const float* feat  = (const float*)d_in[0];
    const float* trans = (const float*)d_in[1];
    const int*   numa  = (const int*)d_in[2];
    float* out = (float*)d_out;

    fafmimo_pipe_kernel<<<dim3(NBLK), dim3(256), 0, stream>>>(
        feat, trans, numa, out);
}